// Round 1
// baseline (39.930 us; speedup 1.0000x reference)
//
#include <hip/hip_runtime.h>

#define HD 1152          // hidden size
#define SQ 4096          // seq len
#define NB 256           // output bins (L)
#define BT 8             // batch
#define KK 4             // pool kernel size

// ---------------------------------------------------------------- kernel 1
// per-batch max over x coordinates (after clamp to >=0); writes max_x = max+1
__global__ void k_maxx(const int* __restrict__ pos, int* __restrict__ maxx) {
    int b = blockIdx.x;
    int tid = threadIdx.x;
    const int* p = pos + (size_t)b * SQ * 2;
    int m = 0;
    for (int i = tid; i < SQ; i += 256) {
        int x = p[2 * i];
        if (x < 0) x = 0;
        m = max(m, x);
    }
    for (int off = 32; off > 0; off >>= 1)
        m = max(m, __shfl_down(m, off, 64));
    __shared__ int sm[4];
    if ((tid & 63) == 0) sm[tid >> 6] = m;
    __syncthreads();
    if (tid == 0) {
        m = max(max(sm[0], sm[1]), max(sm[2], sm[3]));
        maxx[b] = m + 1;
    }
}

// ---------------------------------------------------------------- kernel 2
// per-token flat bin id; -1 for padded tokens
__global__ void k_flat(const int* __restrict__ pos, const int* __restrict__ maxx,
                       int* __restrict__ flat) {
    int idx = blockIdx.x * 256 + threadIdx.x;   // b*SQ + s
    if (idx >= BT * SQ) return;
    int b = idx >> 12;
    int2 xy = ((const int2*)pos)[idx];
    bool pad = (xy.x == -1) && (xy.y == -1);
    int sx = xy.x < 0 ? 0 : xy.x;
    int sy = xy.y < 0 ? 0 : xy.y;
    int f = (sx / KK) + (maxx[b] / KK) * (sy / KK);
    flat[idx] = pad ? -1 : f;
}

// ---------------------------------------------------------------- kernel 3
// one block per (b, bin): ordered ballot-compaction of matching tokens into
// LDS, then gather-sum rows with float4 loads.
__global__ void __launch_bounds__(256) k_pool(const float* __restrict__ hs,
                                              const int* __restrict__ flat,
                                              float* __restrict__ out,
                                              float* __restrict__ mask) {
    int bl = blockIdx.x;          // b*NB + l
    int b = bl >> 8;
    int l = bl & (NB - 1);
    int tid = threadIdx.x;
    int wv = tid >> 6, lane = tid & 63;

    __shared__ unsigned short list[SQ];
    __shared__ int wcnt[4];

    const int* f = flat + b * SQ;
    const int base = wv * (SQ / 4);
    const unsigned long long lanemask = (1ull << lane) - 1ull;

    // pass 1: count matches in this wave's contiguous range
    int cnt = 0;
    for (int c = 0; c < SQ / 4; c += 64) {
        bool m = (f[base + c + lane] == l);
        cnt += __popcll(__ballot(m));
    }
    if (lane == 0) wcnt[wv] = cnt;
    __syncthreads();

    int off = 0;
    #pragma unroll
    for (int w = 0; w < 4; ++w) if (w < wv) off += wcnt[w];
    int total = wcnt[0] + wcnt[1] + wcnt[2] + wcnt[3];

    // pass 2: write ordered token indices
    for (int c = 0; c < SQ / 4; c += 64) {
        bool m = (f[base + c + lane] == l);
        unsigned long long bal = __ballot(m);
        if (m) list[off + __popcll(bal & lanemask)] = (unsigned short)(base + c + lane);
        off += __popcll(bal);
    }
    __syncthreads();

    // gather-sum: 288 float4 per row; thread t owns col4 t (+ t+256 for t<32)
    float4 a0 = make_float4(0.f, 0.f, 0.f, 0.f);
    float4 a1 = make_float4(0.f, 0.f, 0.f, 0.f);
    for (int i = 0; i < total; ++i) {
        int s = list[i];
        const float4* row = (const float4*)(hs + ((size_t)b * SQ + s) * HD);
        float4 v0 = row[tid];
        a0.x += v0.x; a0.y += v0.y; a0.z += v0.z; a0.w += v0.w;
        if (tid < HD / 4 - 256) {          // 288-256 = 32 threads
            float4 v1 = row[256 + tid];
            a1.x += v1.x; a1.y += v1.y; a1.z += v1.z; a1.w += v1.w;
        }
    }

    const float scale = 2.1213203435596424f;   // sqrt(1152) / 16  = 1.5*sqrt(2)
    float4* o = (float4*)(out + (size_t)bl * HD);
    a0.x *= scale; a0.y *= scale; a0.z *= scale; a0.w *= scale;
    o[tid] = a0;
    if (tid < HD / 4 - 256) {
        a1.x *= scale; a1.y *= scale; a1.z *= scale; a1.w *= scale;
        o[256 + tid] = a1;
    }
    if (tid == 0) mask[bl] = (total > 0) ? 1.0f : 0.0f;
}

extern "C" void kernel_launch(void* const* d_in, const int* in_sizes, int n_in,
                              void* d_out, int out_size, void* d_ws, size_t ws_size,
                              hipStream_t stream) {
    const float* hs = (const float*)d_in[0];
    const int* pos = (const int*)d_in[1];
    float* out = (float*)d_out;                       // pooled [8,256,1152]
    float* mask = out + (size_t)BT * NB * HD;         // mask   [8,256]

    int* maxx = (int*)d_ws;                           // 8 ints
    int* flat = maxx + 16;                            // 8*4096 ints (aligned)

    k_maxx<<<BT, 256, 0, stream>>>(pos, maxx);
    k_flat<<<(BT * SQ) / 256, 256, 0, stream>>>(pos, maxx, flat);
    k_pool<<<BT * NB, 256, 0, stream>>>(hs, flat, out, mask);
}

// Round 2
// 35.898 us; speedup vs baseline: 1.1123x; 1.1123x over previous
//
#include <hip/hip_runtime.h>

#define HD 1152          // hidden size
#define SQ 4096          // seq len
#define NB 256           // output bins (L)
#define BT 8             // batch
#define KK 4             // pool kernel size

// ---------------------------------------------------------------- kernel 1
// one block per batch: phase 1 = max over x (clamped >=0), phase 2 = flat bin
// id per token (u16, 0xFFFF for padded). Positions stay in registers between
// phases.
__global__ void __launch_bounds__(1024) k_prep(const int* __restrict__ pos,
                                               unsigned short* __restrict__ flat) {
    int b = blockIdx.x;
    int tid = threadIdx.x;
    const int4* p = (const int4*)(pos + (size_t)b * SQ * 2);   // 2048 int4 (2 tokens each)
    int4 a = p[2 * tid];
    int4 c = p[2 * tid + 1];

    // phase 1: block max of x coords (clamp-after-max is equivalent)
    int mx = max(max(a.x, a.z), max(c.x, c.z));
    if (mx < 0) mx = 0;
    for (int off = 32; off > 0; off >>= 1)
        mx = max(mx, __shfl_down(mx, off, 64));
    __shared__ int sm[16];
    if ((tid & 63) == 0) sm[tid >> 6] = mx;
    __syncthreads();
    if (tid == 0) {
        int v = sm[0];
        #pragma unroll
        for (int i = 1; i < 16; ++i) v = max(v, sm[i]);
        sm[0] = v;
    }
    __syncthreads();
    const int mxq = (sm[0] + 1) / KK;   // (max_x) // k

    // phase 2: flat ids for tokens 4t..4t+3
    #define FLATID(X, Y) ((unsigned short)((((X) == -1) && ((Y) == -1)) ? 0xFFFFu \
        : (unsigned)((max((X), 0) / KK) + mxq * (max((Y), 0) / KK))))
    ushort4 o;
    o.x = FLATID(a.x, a.y);
    o.y = FLATID(a.z, a.w);
    o.z = FLATID(c.x, c.y);
    o.w = FLATID(c.z, c.w);
    ((ushort4*)flat)[(size_t)b * (SQ / 4) + tid] = o;
    #undef FLATID
}

// ---------------------------------------------------------------- kernel 2
// one block per (b, bin): single-pass register-cached compaction (each lane
// owns 16 tokens, loads bin ids as 2x uint4, builds 16-bit match mask, wave
// prefix via shfl_up), then gather-sum matching rows with float4 loads.
__global__ void __launch_bounds__(256) k_pool(const float* __restrict__ hs,
                                              const unsigned short* __restrict__ flat,
                                              float* __restrict__ out,
                                              float* __restrict__ mask) {
    int bl = blockIdx.x;          // b*NB + l
    int b = bl >> 8;
    unsigned l = (unsigned)(bl & (NB - 1));
    int tid = threadIdx.x;
    int wv = tid >> 6, lane = tid & 63;

    __shared__ unsigned short list[SQ];
    __shared__ int wcnt[4];

    // each lane owns tokens [tokbase, tokbase+16)
    const int tokbase = wv * 1024 + lane * 16;
    const unsigned short* f = flat + b * SQ;
    const uint4* fp = (const uint4*)(f + tokbase);   // 32-byte aligned
    uint4 q0 = fp[0];
    uint4 q1 = fp[1];

    unsigned w[8] = {q0.x, q0.y, q0.z, q0.w, q1.x, q1.y, q1.z, q1.w};
    unsigned m16 = 0;
    #pragma unroll
    for (int j = 0; j < 8; ++j) {
        if ((w[j] & 0xFFFFu) == l) m16 |= 1u << (2 * j);
        if ((w[j] >> 16) == l)     m16 |= 1u << (2 * j + 1);
    }
    int cnt = __popc(m16);

    // inclusive prefix sum over 64 lanes
    int pre = cnt;
    #pragma unroll
    for (int off = 1; off < 64; off <<= 1) {
        int n = __shfl_up(pre, off, 64);
        if (lane >= off) pre += n;
    }
    if (lane == 63) wcnt[wv] = pre;     // wave total
    int excl = pre - cnt;               // exclusive prefix within wave
    __syncthreads();

    int woff = 0;
    #pragma unroll
    for (int v = 0; v < 4; ++v) if (v < wv) woff += wcnt[v];
    int total = wcnt[0] + wcnt[1] + wcnt[2] + wcnt[3];

    // scatter matching token indices (deterministic order)
    int r = woff + excl;
    unsigned m = m16;
    while (m) {
        int j = __ffs(m) - 1;
        m &= m - 1;
        list[r++] = (unsigned short)(tokbase + j);
    }
    __syncthreads();

    // gather-sum: 288 float4 per row; thread t owns f4 col t (+ t+256 if t<32)
    float4 a0 = make_float4(0.f, 0.f, 0.f, 0.f);
    float4 a1 = make_float4(0.f, 0.f, 0.f, 0.f);
    const float* hb = hs + (size_t)b * SQ * HD;
    int i = 0;
    for (; i + 1 < total; i += 2) {
        const float4* r0 = (const float4*)(hb + (size_t)list[i] * HD);
        const float4* r1 = (const float4*)(hb + (size_t)list[i + 1] * HD);
        float4 v0 = r0[tid];
        float4 v1 = r1[tid];
        a0.x += v0.x; a0.y += v0.y; a0.z += v0.z; a0.w += v0.w;
        a0.x += v1.x; a0.y += v1.y; a0.z += v1.z; a0.w += v1.w;
        if (tid < HD / 4 - 256) {
            float4 u0 = r0[256 + tid];
            float4 u1 = r1[256 + tid];
            a1.x += u0.x; a1.y += u0.y; a1.z += u0.z; a1.w += u0.w;
            a1.x += u1.x; a1.y += u1.y; a1.z += u1.z; a1.w += u1.w;
        }
    }
    if (i < total) {
        const float4* r0 = (const float4*)(hb + (size_t)list[i] * HD);
        float4 v0 = r0[tid];
        a0.x += v0.x; a0.y += v0.y; a0.z += v0.z; a0.w += v0.w;
        if (tid < HD / 4 - 256) {
            float4 u0 = r0[256 + tid];
            a1.x += u0.x; a1.y += u0.y; a1.z += u0.z; a1.w += u0.w;
        }
    }

    const float scale = 2.1213203435596424f;   // sqrt(1152) / 16
    float4* o = (float4*)(out + (size_t)bl * HD);
    a0.x *= scale; a0.y *= scale; a0.z *= scale; a0.w *= scale;
    o[tid] = a0;
    if (tid < HD / 4 - 256) {
        a1.x *= scale; a1.y *= scale; a1.z *= scale; a1.w *= scale;
        o[256 + tid] = a1;
    }
    if (tid == 0) mask[bl] = (total > 0) ? 1.0f : 0.0f;
}

extern "C" void kernel_launch(void* const* d_in, const int* in_sizes, int n_in,
                              void* d_out, int out_size, void* d_ws, size_t ws_size,
                              hipStream_t stream) {
    const float* hs = (const float*)d_in[0];
    const int* pos = (const int*)d_in[1];
    float* out = (float*)d_out;                        // pooled [8,256,1152]
    float* mask = out + (size_t)BT * NB * HD;          // mask   [8,256]

    unsigned short* flat = (unsigned short*)d_ws;      // 8*4096 u16

    k_prep<<<BT, 1024, 0, stream>>>(pos, flat);
    k_pool<<<BT * NB, 256, 0, stream>>>(hs, flat, out, mask);
}

// Round 3
// 32.123 us; speedup vs baseline: 1.2430x; 1.1175x over previous
//
#include <hip/hip_runtime.h>

#define HD 1152          // hidden size
#define SQ 4096          // seq len
#define NB 256           // output bins (L)
#define BT 8             // batch
#define KK 4             // pool kernel size

// One block per (b, bin). Each of the 256 threads owns 16 consecutive tokens
// (block covers the batch's full 4096 tokens exactly), so:
//   phase 1: per-batch max_x reduce comes free from registers
//   phase 2: flat bin ids in registers, 16-bit match mask, wave prefix-sum
//            compaction into an LDS token list (deterministic order)
//   phase 3: gather-sum the matching rows with float4 loads, 4-deep unroll
__global__ void __launch_bounds__(256) k_pool(const int* __restrict__ pos,
                                              const float* __restrict__ hs,
                                              float* __restrict__ out,
                                              float* __restrict__ mask) {
    int bl = blockIdx.x;          // b*NB + l
    int b = bl >> 8;
    unsigned l = (unsigned)(bl & (NB - 1));
    int tid = threadIdx.x;
    int wv = tid >> 6, lane = tid & 63;

    __shared__ unsigned short list[SQ];
    __shared__ int wcnt[4];
    __shared__ int smax[4];

    // each thread owns tokens [16*tid, 16*tid+16): 32 ints = 8 int4
    const int tokbase = tid * 16;
    const int4* pp = (const int4*)(pos + (size_t)b * SQ * 2) + tid * 8;
    int4 q[8];
    #pragma unroll
    for (int j = 0; j < 8; ++j) q[j] = pp[j];   // {x0,y0,x1,y1} tokens 2j,2j+1

    // ---- phase 1: block max of x (clamped >= 0)
    int mx = 0;
    #pragma unroll
    for (int j = 0; j < 8; ++j) mx = max(mx, max(q[j].x, q[j].z));
    #pragma unroll
    for (int off = 32; off > 0; off >>= 1)
        mx = max(mx, __shfl_down(mx, off, 64));
    if (lane == 0) smax[wv] = mx;
    __syncthreads();
    const int mxq = (max(max(smax[0], smax[1]), max(smax[2], smax[3])) + 1) / KK;

    // ---- phase 2: flat ids + match mask + compaction
    unsigned m16 = 0;
    #pragma unroll
    for (int j = 0; j < 8; ++j) {
        int x0 = q[j].x, y0 = q[j].y, x1 = q[j].z, y1 = q[j].w;
        unsigned f0 = (unsigned)((max(x0, 0) >> 2) + mxq * (max(y0, 0) >> 2));
        unsigned f1 = (unsigned)((max(x1, 0) >> 2) + mxq * (max(y1, 0) >> 2));
        bool p0 = (x0 == -1) && (y0 == -1);
        bool p1 = (x1 == -1) && (y1 == -1);
        if (!p0 && f0 == l) m16 |= 1u << (2 * j);
        if (!p1 && f1 == l) m16 |= 1u << (2 * j + 1);
    }
    int cnt = __popc(m16);

    int pre = cnt;                      // inclusive wave prefix
    #pragma unroll
    for (int off = 1; off < 64; off <<= 1) {
        int n = __shfl_up(pre, off, 64);
        if (lane >= off) pre += n;
    }
    if (lane == 63) wcnt[wv] = pre;
    int excl = pre - cnt;
    __syncthreads();

    int woff = 0;
    #pragma unroll
    for (int v = 0; v < 4; ++v) if (v < wv) woff += wcnt[v];
    int total = wcnt[0] + wcnt[1] + wcnt[2] + wcnt[3];

    int r = woff + excl;
    unsigned m = m16;
    while (m) {
        int j = __ffs(m) - 1;
        m &= m - 1;
        list[r++] = (unsigned short)(tokbase + j);
    }
    __syncthreads();

    // ---- phase 3: gather-sum (288 float4/row; thread t owns col4 t, +t+256 if t<32)
    float4 a0 = make_float4(0.f, 0.f, 0.f, 0.f);
    float4 a1 = make_float4(0.f, 0.f, 0.f, 0.f);
    const float* hb = hs + (size_t)b * SQ * HD;
    int i = 0;
    for (; i + 3 < total; i += 4) {
        const float4* r0 = (const float4*)(hb + (size_t)list[i]     * HD);
        const float4* r1 = (const float4*)(hb + (size_t)list[i + 1] * HD);
        const float4* r2 = (const float4*)(hb + (size_t)list[i + 2] * HD);
        const float4* r3 = (const float4*)(hb + (size_t)list[i + 3] * HD);
        float4 v0 = r0[tid], v1 = r1[tid], v2 = r2[tid], v3 = r3[tid];
        a0.x += v0.x + v1.x + v2.x + v3.x;
        a0.y += v0.y + v1.y + v2.y + v3.y;
        a0.z += v0.z + v1.z + v2.z + v3.z;
        a0.w += v0.w + v1.w + v2.w + v3.w;
        if (tid < HD / 4 - 256) {
            float4 u0 = r0[256 + tid], u1 = r1[256 + tid];
            float4 u2 = r2[256 + tid], u3 = r3[256 + tid];
            a1.x += u0.x + u1.x + u2.x + u3.x;
            a1.y += u0.y + u1.y + u2.y + u3.y;
            a1.z += u0.z + u1.z + u2.z + u3.z;
            a1.w += u0.w + u1.w + u2.w + u3.w;
        }
    }
    for (; i < total; ++i) {
        const float4* r0 = (const float4*)(hb + (size_t)list[i] * HD);
        float4 v0 = r0[tid];
        a0.x += v0.x; a0.y += v0.y; a0.z += v0.z; a0.w += v0.w;
        if (tid < HD / 4 - 256) {
            float4 u0 = r0[256 + tid];
            a1.x += u0.x; a1.y += u0.y; a1.z += u0.z; a1.w += u0.w;
        }
    }

    const float scale = 2.1213203435596424f;   // sqrt(1152) / 16
    float4* o = (float4*)(out + (size_t)bl * HD);
    a0.x *= scale; a0.y *= scale; a0.z *= scale; a0.w *= scale;
    o[tid] = a0;
    if (tid < HD / 4 - 256) {
        a1.x *= scale; a1.y *= scale; a1.z *= scale; a1.w *= scale;
        o[256 + tid] = a1;
    }
    if (tid == 0) mask[bl] = (total > 0) ? 1.0f : 0.0f;
}

extern "C" void kernel_launch(void* const* d_in, const int* in_sizes, int n_in,
                              void* d_out, int out_size, void* d_ws, size_t ws_size,
                              hipStream_t stream) {
    const float* hs = (const float*)d_in[0];
    const int* pos = (const int*)d_in[1];
    float* out = (float*)d_out;                        // pooled [8,256,1152]
    float* mask = out + (size_t)BT * NB * HD;          // mask   [8,256]

    k_pool<<<BT * NB, 256, 0, stream>>>(pos, hs, out, mask);
}